// Round 17
// baseline (299.054 us; speedup 1.0000x reference)
//
#include <hip/hip_runtime.h>
#include <hip/hip_bf16.h>
#include <stdint.h>

typedef __attribute__((ext_vector_type(8))) short bf16x8;
typedef __attribute__((ext_vector_type(4))) float f32x4v;
typedef __attribute__((ext_vector_type(16))) float f32x16;

#define CH_STRIDE 65536  // T*W*H

__device__ __forceinline__ uint16_t f2bf(float f) {
  uint32_t u = __builtin_bit_cast(uint32_t, f);
  u = (u + 0x7FFFu + ((u >> 16) & 1u)) >> 16;
  return (uint16_t)u;
}
__device__ __forceinline__ float bf2f(uint32_t b) {
  return __builtin_bit_cast(float, b << 16);
}
__device__ __forceinline__ uint16_t cvt_bf(float f) {
  return __builtin_bit_cast(uint16_t, __float2bfloat16(f));
}

#define MFMA32(a, b, c) __builtin_amdgcn_mfma_f32_32x32x16_bf16(a, b, c, 0, 0, 0)
#define LGKM0 asm volatile("s_waitcnt lgkmcnt(0)" ::: "memory")
#define BAR __builtin_amdgcn_s_barrier()
#define SCHED0 __builtin_amdgcn_sched_barrier(0)

#define LDSX6  (6 * 8 * 66 * 16)   // 50688 (q kernel)
#define LDSX10 (10 * 8 * 66 * 16)  // 84480 (kv kernel)

__device__ __forceinline__ uint32_t swz(uint32_t b) {
  return b ^ (((b >> 7) & 7u) << 4);
}

__device__ __forceinline__ bf16x8 ldx(const uint8_t* ldsx, int row, int oct, int ci) {
  return *(const bf16x8*)(ldsx + swz((uint32_t)((row * 8 + oct) * 66 + ci) * 16u));
}

__device__ __forceinline__ void stage_unit(uint8_t* ldsx, const float* xs, int w0, int u) {
  int row = u >> 7, oct = (u >> 4) & 7, g = u & 15;
  int w = w0 - 1 + row;
  uint32_t base = (uint32_t)((row * 8 + oct) * 66 + 4 * g + 1) * 16u;
  if ((unsigned)w < 64u) {
    const float* p = xs + (size_t)(oct * 8) * CH_STRIDE + w * 64 + 4 * g;
    f32x4v v[8];
    #pragma unroll
    for (int j = 0; j < 8; ++j) v[j] = *(const f32x4v*)(p + (size_t)j * CH_STRIDE);
    #pragma unroll
    for (int c = 0; c < 4; ++c) {
      bf16x8 frag;
      #pragma unroll
      for (int q = 0; q < 4; ++q) {
        frag[2 * q]     = (short)cvt_bf(v[2 * q][c]);
        frag[2 * q + 1] = (short)cvt_bf(v[2 * q + 1][c]);
      }
      *(bf16x8*)(ldsx + swz(base + (uint32_t)c * 16u)) = frag;
    }
  } else {
    bf16x8 z = {};
    #pragma unroll
    for (int c = 0; c < 4; ++c)
      *(bf16x8*)(ldsx + swz(base + (uint32_t)c * 16u)) = z;
  }
}
__device__ __forceinline__ void stage_halo(uint8_t* ldsx, int tid, int nrow) {
  if (tid < nrow * 16) {
    int row = tid >> 4, rem = tid & 15;
    int oct = rem >> 1, side = rem & 1;
    bf16x8 z = {};
    *(bf16x8*)(ldsx + swz((uint32_t)((row * 8 + oct) * 66 + side * 65) * 16u)) = z;
  }
}
__device__ __forceinline__ void stage_x256(uint8_t* ldsx, const float* xs, int w0, int tid) {
  stage_halo(ldsx, tid, 6);
  #pragma unroll
  for (int k = 0; k < 3; ++k) stage_unit(ldsx, xs, w0, tid + k * 256);
}
__device__ __forceinline__ void stage_x1024(uint8_t* ldsx, const float* xs, int w0, int tid) {
  stage_halo(ldsx, tid, 10);
  stage_unit(ldsx, xs, w0, tid);
  if (tid < 256) stage_unit(ldsx, xs, w0, 1024 + tid);
}

__device__ __forceinline__ bf16x8 ldw_kv(const uint8_t* ldsw, int oct, int rowloc) {
  return *(const bf16x8*)(ldsw + (uint32_t)(oct * 128 + rowloc) * 16u);
}
__device__ __forceinline__ bf16x8 ldw_q(const uint8_t* ldsw, int oct, int row) {
  return *(const bf16x8*)(ldsw + (uint32_t)(oct * 64 + row) * 16u);
}
__device__ __forceinline__ void ldw_g_q(bf16x8* r, const uint16_t* wq, int tap, int tid) {
  #pragma unroll
  for (int k = 0; k < 2; ++k)
    r[k] = *(const bf16x8*)(wq + ((size_t)tap * 512 + tid + k * 256) * 8);
}
__device__ __forceinline__ void stw_q(uint8_t* ldsw, const bf16x8* r, int tid) {
  #pragma unroll
  for (int k = 0; k < 2; ++k)
    *(bf16x8*)(ldsw + (uint32_t)(tid + k * 256) * 16u) = r[k];
}

// ---------------------------------------------------------------------------
__global__ void prep_weights(const float* __restrict__ wq, const float* __restrict__ wk,
                             const float* __restrict__ wv, uint16_t* __restrict__ wout) {
  int i = blockIdx.x * 256 + threadIdx.x;
  if (i >= 110592) return;
  if (i < 36864) {
    int tap = i >> 12, oct = (i >> 9) & 7, row = (i >> 3) & 63, j = i & 7;
    wout[i] = f2bf(wq[(row * 64 + oct * 8 + j) * 9 + tap]);
  } else {
    int m = i - 36864;
    int tap = m >> 13, oct = (m >> 10) & 7, rl = (m >> 3) & 127, j = m & 7;
    const float* src = (rl < 64) ? wk : wv;
    wout[i] = f2bf(src[((rl & 63) * 64 + oct * 8 + j) * 9 + tap]);
  }
}

// ---------------------------------------------------------------------------
// KV kernel body, shared by real path (V=0) and probes:
// V=1: no stage_x (isolate stage cost). V=2: x-frags hoisted pre-loop
// (isolate per-tap x-LDS-read cost). Structure otherwise identical.
// ---------------------------------------------------------------------------
template <int V>
__device__ __forceinline__ void kv_body(
    const float* __restrict__ x, const uint16_t* __restrict__ wkv,
    const float* __restrict__ bk, const float* __restrict__ bv,
    float* __restrict__ s_out) {
  extern __shared__ uint8_t lds[];
  uint8_t* ldsx = lds;
  uint8_t* ldswA = lds + LDSX10;
  uint8_t* ldswB = lds + LDSX10 + 16384;
  const int tid = threadIdx.x;
  const int l = tid & 63;
  const int wid = tid >> 6;
  const int ng = wid & 7, mg = wid >> 3;
  int bid = (int)(blockIdx.x & 7) * 128 + (int)(blockIdx.x >> 3);  // XCD swizzle
  const int rg = bid & 7, slice = bid >> 3;
  const int b = slice >> 4, t = slice & 15;
  const int w0 = rg * 8;
  const float* xs = x + ((size_t)b * 1024 + t) * 4096;
  const int lm = l & 31, lh = l >> 5;

  if constexpr (V != 1) stage_x1024(ldsx, xs, w0, tid);
  bf16x8 r_pref;
  r_pref = *(const bf16x8*)(wkv + (size_t)tid * 8);
  *(bf16x8*)(ldswA + (uint32_t)tid * 16u) = r_pref;
  r_pref = *(const bf16x8*)(wkv + ((size_t)1024 + tid) * 8);
  SCHED0; LGKM0; BAR; SCHED0;

  // V=2: hoist x-fragments (dy=dx=0 proxy) into registers before the loop.
  bf16x8 hx0[4], hx1[4];
  if constexpr (V == 2) {
    #pragma unroll
    for (int s = 0; s < 4; ++s) {
      int oct = s * 2 + lh;
      hx0[s] = ldx(ldsx, ng, oct, lm);
      hx1[s] = ldx(ldsx, ng, oct, 32 + lm);
    }
  }

  f32x16 accK[2], accV[2];
  #pragma unroll
  for (int nt = 0; nt < 2; ++nt)
    #pragma unroll
    for (int q = 0; q < 16; ++q) { accK[nt][q] = 0.f; accV[nt][q] = 0.f; }

  #pragma unroll
  for (int tap = 0; tap < 9; ++tap) {
    const int dy = tap / 3, dx = tap % 3;
    const uint8_t* bufc = (tap & 1) ? ldswB : ldswA;
    uint8_t* bufn = (tap & 1) ? ldswA : ldswB;
    int oct0 = lh;
    bf16x8 aK = ldw_kv(bufc, oct0, mg * 32 + lm);
    bf16x8 aV = ldw_kv(bufc, oct0, 64 + mg * 32 + lm);
    bf16x8 b0, b1;
    if constexpr (V == 2) { b0 = hx0[0]; b1 = hx1[0]; }
    else { b0 = ldx(ldsx, ng + dy, oct0, lm + dx); b1 = ldx(ldsx, ng + dy, oct0, 32 + lm + dx); }
    if (tap < 8) {
      *(bf16x8*)(bufn + (uint32_t)tid * 16u) = r_pref;
      if (tap < 7)
        r_pref = *(const bf16x8*)(wkv + ((size_t)(tap + 2) * 1024 + tid) * 8);
    }
    __builtin_amdgcn_s_setprio(1);
    accK[0] = MFMA32(aK, b0, accK[0]);
    accK[1] = MFMA32(aK, b1, accK[1]);
    accV[0] = MFMA32(aV, b0, accV[0]);
    accV[1] = MFMA32(aV, b1, accV[1]);
    #pragma unroll
    for (int s = 1; s < 4; ++s) {
      int oct = s * 2 + lh;
      aK = ldw_kv(bufc, oct, mg * 32 + lm);
      aV = ldw_kv(bufc, oct, 64 + mg * 32 + lm);
      if constexpr (V == 2) { b0 = hx0[s]; b1 = hx1[s]; }
      else { b0 = ldx(ldsx, ng + dy, oct, lm + dx); b1 = ldx(ldsx, ng + dy, oct, 32 + lm + dx); }
      accK[0] = MFMA32(aK, b0, accK[0]);
      accK[1] = MFMA32(aK, b1, accK[1]);
      accV[0] = MFMA32(aV, b0, accV[0]);
      accV[1] = MFMA32(aV, b1, accV[1]);
    }
    __builtin_amdgcn_s_setprio(0);
    SCHED0; LGKM0; BAR; SCHED0;
  }

  // epilogue: LDS partial-dump (stride 261: conflict-free reduce), 1 atomic/ch
  __syncthreads();
  float* red = (float*)lds;        // [c 64][261] = 66.8 KB
  #pragma unroll
  for (int q = 0; q < 16; ++q) {
    int cl = (q & 3) + 8 * (q >> 2) + 4 * lh;
    int c = mg * 32 + cl;
    float bkc = bk[c], bvc = bv[c];
    float p = (accK[0][q] + bkc) * (accV[0][q] + bvc)
            + (accK[1][q] + bkc) * (accV[1][q] + bvc);
    red[c * 261 + ng * 32 + lm] = p;
  }
  __syncthreads();
  if (tid < 64) {
    const float* rp = red + tid * 261;
    f32x4v a4 = {0.f, 0.f, 0.f, 0.f};
    #pragma unroll
    for (int j = 0; j < 64; ++j) a4 += *(const f32x4v*)(rp + j * 4);
    atomicAdd(s_out + (b * 16 + t) * 64 + tid, a4[0] + a4[1] + a4[2] + a4[3]);
  }
}

__global__ __launch_bounds__(1024, 4) void kv_s_kernel(
    const float* __restrict__ x, const uint16_t* __restrict__ wkv,
    const float* __restrict__ bk, const float* __restrict__ bv,
    float* __restrict__ s_out) {
  kv_body<0>(x, wkv, bk, bv, s_out);
}
__global__ __launch_bounds__(1024, 4) void kv_probe_nostage(
    const float* __restrict__ x, const uint16_t* __restrict__ wkv,
    const float* __restrict__ bk, const float* __restrict__ bv,
    float* __restrict__ s_out) {
  kv_body<1>(x, wkv, bk, bv, s_out);
}
__global__ __launch_bounds__(1024, 4) void kv_probe_hoistx(
    const float* __restrict__ x, const uint16_t* __restrict__ wkv,
    const float* __restrict__ bk, const float* __restrict__ bv,
    float* __restrict__ s_out) {
  kv_body<2>(x, wkv, bk, bv, s_out);
}

// ---------------------------------------------------------------------------
// Q kernel (unchanged — control, at HBM floor).
// ---------------------------------------------------------------------------
__global__ __launch_bounds__(256, 2) void q_out_kernel(
    const float* __restrict__ x, const uint16_t* __restrict__ wq,
    const float* __restrict__ bq, const float* __restrict__ s_in,
    const float* __restrict__ gamma, float* __restrict__ out) {
  extern __shared__ uint8_t lds[];
  uint8_t* ldsx = lds;
  uint8_t* ldsw = lds + LDSX6;
  const int tid = threadIdx.x;
  const int l = tid & 63, ng = tid >> 6;
  int bid = (int)(blockIdx.x & 7) * 256 + (int)(blockIdx.x >> 3);  // XCD swizzle
  const int rg = bid & 15, slice = bid >> 4;
  const int b = slice >> 4, t = slice & 15;
  const int w0 = rg * 4;
  const float* xs = x + ((size_t)b * 1024 + t) * 4096;
  const int lm = l & 31, lh = l >> 5;

  stage_x256(ldsx, xs, w0, tid);
  bf16x8 r[2];
  ldw_g_q(r, wq, 0, tid);
  stw_q(ldsw, r, tid);
  ldw_g_q(r, wq, 1, tid);
  SCHED0; LGKM0; BAR; SCHED0;

  f32x16 acc[2][2];
  #pragma unroll
  for (int mt = 0; mt < 2; ++mt)
    #pragma unroll
    for (int nt = 0; nt < 2; ++nt)
      #pragma unroll
      for (int q = 0; q < 16; ++q) acc[mt][nt][q] = 0.f;

  #pragma unroll
  for (int tap = 0; tap < 9; ++tap) {
    const int dy = tap / 3, dx = tap % 3;
    __builtin_amdgcn_s_setprio(1);
    #pragma unroll
    for (int s = 0; s < 4; ++s) {
      int oct = s * 2 + lh;
      bf16x8 a0 = ldw_q(ldsw, oct, lm);
      bf16x8 a1 = ldw_q(ldsw, oct, 32 + lm);
      bf16x8 b0 = ldx(ldsx, ng + dy, oct, lm + dx);
      bf16x8 b1 = ldx(ldsx, ng + dy, oct, 32 + lm + dx);
      acc[0][0] = MFMA32(a0, b0, acc[0][0]);
      acc[0][1] = MFMA32(a0, b1, acc[0][1]);
      acc[1][0] = MFMA32(a1, b0, acc[1][0]);
      acc[1][1] = MFMA32(a1, b1, acc[1][1]);
    }
    __builtin_amdgcn_s_setprio(0);
    if (tap < 8) {
      SCHED0; BAR;
      stw_q(ldsw, r, tid);
      if (tap < 7) ldw_g_q(r, wq, tap + 2, tid);
      SCHED0; LGKM0; BAR; SCHED0;
    }
  }

  float g = gamma[0];
  const float* sb = s_in + (b * 16 + t) * 64;
  int w = w0 + ng;
  #pragma unroll
  for (int mt = 0; mt < 2; ++mt) {
    #pragma unroll
    for (int q = 0; q < 16; ++q) {
      int cl = (q & 3) + 8 * (q >> 2) + 4 * lh;
      int c  = mt * 32 + cl;
      float qb = bq[c], sc = sb[c];
      #pragma unroll
      for (int nt = 0; nt < 2; ++nt) {
        int h = nt * 32 + lm;
        uint32_t xb = (uint32_t)(((ng + 1) * 8 + (c >> 3)) * 66 + (h + 1)) * 16u
                    + (uint32_t)(c & 7) * 2u;
        float xv = bf2f(*(const uint16_t*)(ldsx + swz(xb)));
        size_t idx = ((size_t)(b * 64 + c) * 16 + t) * 4096 + (size_t)w * 64 + h;
        out[idx] = g * (acc[mt][nt][q] + qb) * sc + xv;
      }
    }
  }
}

extern "C" void kernel_launch(void* const* d_in, const int* in_sizes, int n_in,
                              void* d_out, int out_size, void* d_ws, size_t ws_size,
                              hipStream_t stream) {
  const float* x   = (const float*)d_in[0];
  const float* wq  = (const float*)d_in[1];
  const float* wk  = (const float*)d_in[2];
  const float* wv  = (const float*)d_in[3];
  const float* bq  = (const float*)d_in[4];
  const float* bk  = (const float*)d_in[5];
  const float* bv  = (const float*)d_in[6];
  const float* gam = (const float*)d_in[7];

  uint16_t* wbf   = (uint16_t*)d_ws;                    // 221184 B
  float* sbuf     = (float*)((uint8_t*)d_ws + 221184);  // 32 KB
  float* pscratch = (float*)((uint8_t*)d_ws + 1048576); // probe scratch 32 KB

  hipMemsetAsync(sbuf, 0, 8 * 16 * 64 * sizeof(float), stream);
  prep_weights<<<(110592 + 255) / 256, 256, 0, stream>>>(wq, wk, wv, wbf);
  // Real path:
  kv_s_kernel<<<1024, 1024, LDSX10 + 32768, stream>>>(x, wbf + 36864, bk, bv, sbuf);
  q_out_kernel<<<2048, 256, LDSX6 + 8192, stream>>>(x, wbf, bq, sbuf, gam, (float*)d_out);
  // Diagnostic probes (scratch only; read per-dispatch dur_us from rocprof):
  kv_probe_nostage<<<1024, 1024, LDSX10 + 32768, stream>>>(x, wbf + 36864, bk, bv, pscratch);
  kv_probe_hoistx<<<1024, 1024, LDSX10 + 32768, stream>>>(x, wbf + 36864, bk, bv, pscratch);
}

// Round 18
// 181.768 us; speedup vs baseline: 1.6452x; 1.6452x over previous
//
#include <hip/hip_runtime.h>
#include <hip/hip_bf16.h>
#include <stdint.h>

typedef __attribute__((ext_vector_type(8))) short bf16x8;
typedef __attribute__((ext_vector_type(4))) float f32x4v;
typedef __attribute__((ext_vector_type(16))) float f32x16;

#define CH_STRIDE 65536   // x: T*W*H floats per channel
#define ROW_B 8448        // xT bytes per w' row = 8*66*16
#define SLICE_B 557568    // xT bytes per slice = 66 rows * ROW_B

__device__ __forceinline__ uint16_t f2bf(float f) {
  uint32_t u = __builtin_bit_cast(uint32_t, f);
  u = (u + 0x7FFFu + ((u >> 16) & 1u)) >> 16;
  return (uint16_t)u;
}
__device__ __forceinline__ float bf2f(uint32_t b) {
  return __builtin_bit_cast(float, b << 16);
}
__device__ __forceinline__ uint16_t cvt_bf(float f) {
  return __builtin_bit_cast(uint16_t, __float2bfloat16(f));
}

#define MFMA32(a, b, c) __builtin_amdgcn_mfma_f32_32x32x16_bf16(a, b, c, 0, 0, 0)
#define LGKM0 asm volatile("s_waitcnt lgkmcnt(0)" ::: "memory")
#define BAR __builtin_amdgcn_s_barrier()
#define SCHED0 __builtin_amdgcn_sched_barrier(0)

#define LDSX6  (6 * 8 * 66 * 16)   // 50688 (q kernel x tile)
#define LDSX10 (10 * 8 * 66 * 16)  // 84480 (kv kernel x tile)

// x tile in LDS: [row][oct][col66] 16B frags, LINEAR (no swizzle needed:
// stage writes and frag reads are both contiguous runs).
__device__ __forceinline__ bf16x8 ldx(const uint8_t* ldsx, int row, int oct, int ci) {
  return *(const bf16x8*)(ldsx + (uint32_t)((row * 8 + oct) * 66 + ci) * 16u);
}

__device__ __forceinline__ bf16x8 ldw_kv(const uint8_t* ldsw, int oct, int rowloc) {
  return *(const bf16x8*)(ldsw + (uint32_t)(oct * 128 + rowloc) * 16u);
}
__device__ __forceinline__ bf16x8 ldw_q(const uint8_t* ldsw, int oct, int row) {
  return *(const bf16x8*)(ldsw + (uint32_t)(oct * 64 + row) * 16u);
}
__device__ __forceinline__ void ldw_g_q(bf16x8* r, const uint16_t* wq, int tap, int tid) {
  #pragma unroll
  for (int k = 0; k < 2; ++k)
    r[k] = *(const bf16x8*)(wq + ((size_t)tap * 512 + tid + k * 256) * 8);
}
__device__ __forceinline__ void stw_q(uint8_t* ldsw, const bf16x8* r, int tid) {
  #pragma unroll
  for (int k = 0; k < 2; ++k)
    *(bf16x8*)(ldsw + (uint32_t)(tid + k * 256) * 16u) = r[k];
}

// ---------------------------------------------------------------------------
// prep: fp32 [o][i][tap] -> bf16 tap-contiguous tables (q then kv).
// ---------------------------------------------------------------------------
__global__ void prep_weights(const float* __restrict__ wq, const float* __restrict__ wk,
                             const float* __restrict__ wv, uint16_t* __restrict__ wout) {
  int i = blockIdx.x * 256 + threadIdx.x;
  if (i >= 110592) return;
  if (i < 36864) {
    int tap = i >> 12, oct = (i >> 9) & 7, row = (i >> 3) & 63, j = i & 7;
    wout[i] = f2bf(wq[(row * 64 + oct * 8 + j) * 9 + tap]);
  } else {
    int m = i - 36864;
    int tap = m >> 13, oct = (m >> 10) & 7, rl = (m >> 3) & 127, j = m & 7;
    const float* src = (rl < 64) ? wk : wv;
    wout[i] = f2bf(src[((rl & 63) * 64 + oct * 8 + j) * 9 + tap]);
  }
}

// ---------------------------------------------------------------------------
// transpose_x: x fp32 -> xT bf16 [slice][w' 0..65][oct][col66] 16B frags.
// w' = w+1 (w'=0,65 are zero halo rows); col 0,65 are zero halo cols.
// After this, every kernel stage is a contiguous memcpy.
// ---------------------------------------------------------------------------
__global__ __launch_bounds__(256, 4) void transpose_x(const float* __restrict__ x,
                                                      uint8_t* __restrict__ xT) {
  __shared__ uint8_t lds[4 * 8 * 66 * 16];
  const int tid = threadIdx.x;
  const int bid = blockIdx.x;
  const int gg = bid % 17, slice = bid / 17;
  const int b = slice >> 4, t = slice & 15;
  const int r0 = gg * 4;
  const int nrow = (gg == 16) ? 2 : 4;
  const float* xs = x + ((size_t)b * 1024 + t) * 4096;

  if (tid < nrow * 16) {  // col halos
    int row = tid >> 4, rem = tid & 15;
    int oct = rem >> 1, side = rem & 1;
    bf16x8 z = {};
    *(bf16x8*)(lds + (uint32_t)((row * 8 + oct) * 66 + side * 65) * 16u) = z;
  }
  #pragma unroll
  for (int k = 0; k < 2; ++k) {
    int u = tid + k * 256;
    if (u < nrow * 128) {
      int row = u >> 7, oct = (u >> 4) & 7, g = u & 15;
      int w = r0 + row - 1;  // w' = r0+row
      uint32_t base = (uint32_t)((row * 8 + oct) * 66 + 4 * g + 1) * 16u;
      if ((unsigned)w < 64u) {
        const float* p = xs + (size_t)(oct * 8) * CH_STRIDE + w * 64 + 4 * g;
        f32x4v v[8];
        #pragma unroll
        for (int j = 0; j < 8; ++j) v[j] = *(const f32x4v*)(p + (size_t)j * CH_STRIDE);
        #pragma unroll
        for (int c = 0; c < 4; ++c) {
          bf16x8 frag;
          #pragma unroll
          for (int q = 0; q < 4; ++q) {
            frag[2 * q]     = (short)cvt_bf(v[2 * q][c]);
            frag[2 * q + 1] = (short)cvt_bf(v[2 * q + 1][c]);
          }
          *(bf16x8*)(lds + base + (uint32_t)c * 16u) = frag;
        }
      } else {
        bf16x8 z = {};
        #pragma unroll
        for (int c = 0; c < 4; ++c)
          *(bf16x8*)(lds + base + (uint32_t)c * 16u) = z;
      }
    }
  }
  __syncthreads();
  uint8_t* dst = xT + (size_t)slice * SLICE_B + (size_t)r0 * 528 * 16;
  for (int i = tid; i < nrow * 528; i += 256)
    *(bf16x8*)(dst + (uint32_t)i * 16u) = *(const bf16x8*)(lds + (uint32_t)i * 16u);
}

// ---------------------------------------------------------------------------
// KV kernel: 1024 thr / 16 waves = (mg hi-bit, ng row 0-7); 8-row tile.
// Stage = contiguous 84.5KB memcpy from xT. Loop/epilogue = R16 (validated).
// ---------------------------------------------------------------------------
__global__ __launch_bounds__(1024, 4) void kv_s_kernel(
    const uint8_t* __restrict__ xT, const uint16_t* __restrict__ wkv,
    const float* __restrict__ bk, const float* __restrict__ bv,
    float* __restrict__ s_out) {
  extern __shared__ uint8_t lds[];
  uint8_t* ldsx = lds;
  uint8_t* ldswA = lds + LDSX10;
  uint8_t* ldswB = lds + LDSX10 + 16384;
  const int tid = threadIdx.x;
  const int l = tid & 63;
  const int wid = tid >> 6;
  const int ng = wid & 7, mg = wid >> 3;
  int bid = (int)(blockIdx.x & 7) * 128 + (int)(blockIdx.x >> 3);  // XCD swizzle
  const int rg = bid & 7, slice = bid >> 3;
  const int b = slice >> 4, t = slice & 15;
  const int w0 = rg * 8;
  const int lm = l & 31, lh = l >> 5;

  // stage: rows w' = w0..w0+9 are 84480 contiguous bytes in xT
  const uint8_t* gx = xT + (size_t)slice * SLICE_B + (size_t)w0 * ROW_B;
  #pragma unroll
  for (int k = 0; k < 6; ++k) {
    int idx = tid + k * 1024;
    if (idx < 5280)
      *(bf16x8*)(ldsx + (uint32_t)idx * 16u) = *(const bf16x8*)(gx + (uint32_t)idx * 16u);
  }
  bf16x8 r_pref;
  r_pref = *(const bf16x8*)(wkv + (size_t)tid * 8);
  *(bf16x8*)(ldswA + (uint32_t)tid * 16u) = r_pref;
  r_pref = *(const bf16x8*)(wkv + ((size_t)1024 + tid) * 8);
  SCHED0; LGKM0; BAR; SCHED0;

  f32x16 accK[2], accV[2];
  #pragma unroll
  for (int nt = 0; nt < 2; ++nt)
    #pragma unroll
    for (int q = 0; q < 16; ++q) { accK[nt][q] = 0.f; accV[nt][q] = 0.f; }

  #pragma unroll
  for (int tap = 0; tap < 9; ++tap) {
    const int dy = tap / 3, dx = tap % 3;
    const uint8_t* bufc = (tap & 1) ? ldswB : ldswA;
    uint8_t* bufn = (tap & 1) ? ldswA : ldswB;
    int oct0 = lh;
    bf16x8 aK = ldw_kv(bufc, oct0, mg * 32 + lm);
    bf16x8 aV = ldw_kv(bufc, oct0, 64 + mg * 32 + lm);
    bf16x8 b0 = ldx(ldsx, ng + dy, oct0, lm + dx);
    bf16x8 b1 = ldx(ldsx, ng + dy, oct0, 32 + lm + dx);
    if (tap < 8) {
      *(bf16x8*)(bufn + (uint32_t)tid * 16u) = r_pref;
      if (tap < 7)
        r_pref = *(const bf16x8*)(wkv + ((size_t)(tap + 2) * 1024 + tid) * 8);
    }
    __builtin_amdgcn_s_setprio(1);
    accK[0] = MFMA32(aK, b0, accK[0]);
    accK[1] = MFMA32(aK, b1, accK[1]);
    accV[0] = MFMA32(aV, b0, accV[0]);
    accV[1] = MFMA32(aV, b1, accV[1]);
    #pragma unroll
    for (int s = 1; s < 4; ++s) {
      int oct = s * 2 + lh;
      aK = ldw_kv(bufc, oct, mg * 32 + lm);
      aV = ldw_kv(bufc, oct, 64 + mg * 32 + lm);
      b0 = ldx(ldsx, ng + dy, oct, lm + dx);
      b1 = ldx(ldsx, ng + dy, oct, 32 + lm + dx);
      accK[0] = MFMA32(aK, b0, accK[0]);
      accK[1] = MFMA32(aK, b1, accK[1]);
      accV[0] = MFMA32(aV, b0, accV[0]);
      accV[1] = MFMA32(aV, b1, accV[1]);
    }
    __builtin_amdgcn_s_setprio(0);
    SCHED0; LGKM0; BAR; SCHED0;
  }

  // epilogue: LDS partial-dump (stride 261), 64-thread reduce, 1 atomic/ch
  __syncthreads();
  float* red = (float*)lds;        // [c 64][261] = 66.8 KB
  #pragma unroll
  for (int q = 0; q < 16; ++q) {
    int cl = (q & 3) + 8 * (q >> 2) + 4 * lh;
    int c = mg * 32 + cl;
    float bkc = bk[c], bvc = bv[c];
    float p = (accK[0][q] + bkc) * (accV[0][q] + bvc)
            + (accK[1][q] + bkc) * (accV[1][q] + bvc);
    red[c * 261 + ng * 32 + lm] = p;
  }
  __syncthreads();
  if (tid < 64) {
    const float* rp = red + tid * 261;
    f32x4v a4 = {0.f, 0.f, 0.f, 0.f};
    #pragma unroll
    for (int j = 0; j < 64; ++j) a4 += *(const f32x4v*)(rp + j * 4);
    atomicAdd(s_out + (b * 16 + t) * 64 + tid, a4[0] + a4[1] + a4[2] + a4[3]);
  }
}

// ---------------------------------------------------------------------------
// Q kernel: stage = contiguous 50.7KB memcpy from xT; residual from ldsx.
// ---------------------------------------------------------------------------
__global__ __launch_bounds__(256, 2) void q_out_kernel(
    const uint8_t* __restrict__ xT, const uint16_t* __restrict__ wq,
    const float* __restrict__ bq, const float* __restrict__ s_in,
    const float* __restrict__ gamma, float* __restrict__ out) {
  extern __shared__ uint8_t lds[];
  uint8_t* ldsx = lds;
  uint8_t* ldsw = lds + LDSX6;
  const int tid = threadIdx.x;
  const int l = tid & 63, ng = tid >> 6;
  int bid = (int)(blockIdx.x & 7) * 256 + (int)(blockIdx.x >> 3);  // XCD swizzle
  const int rg = bid & 15, slice = bid >> 4;
  const int b = slice >> 4, t = slice & 15;
  const int w0 = rg * 4;
  const int lm = l & 31, lh = l >> 5;

  const uint8_t* gx = xT + (size_t)slice * SLICE_B + (size_t)w0 * ROW_B;
  #pragma unroll
  for (int k = 0; k < 13; ++k) {
    int idx = tid + k * 256;
    if (idx < 3168)
      *(bf16x8*)(ldsx + (uint32_t)idx * 16u) = *(const bf16x8*)(gx + (uint32_t)idx * 16u);
  }
  bf16x8 r[2];
  ldw_g_q(r, wq, 0, tid);
  stw_q(ldsw, r, tid);
  ldw_g_q(r, wq, 1, tid);
  SCHED0; LGKM0; BAR; SCHED0;

  f32x16 acc[2][2];
  #pragma unroll
  for (int mt = 0; mt < 2; ++mt)
    #pragma unroll
    for (int nt = 0; nt < 2; ++nt)
      #pragma unroll
      for (int q = 0; q < 16; ++q) acc[mt][nt][q] = 0.f;

  #pragma unroll
  for (int tap = 0; tap < 9; ++tap) {
    const int dy = tap / 3, dx = tap % 3;
    __builtin_amdgcn_s_setprio(1);
    #pragma unroll
    for (int s = 0; s < 4; ++s) {
      int oct = s * 2 + lh;
      bf16x8 a0 = ldw_q(ldsw, oct, lm);
      bf16x8 a1 = ldw_q(ldsw, oct, 32 + lm);
      bf16x8 b0 = ldx(ldsx, ng + dy, oct, lm + dx);
      bf16x8 b1 = ldx(ldsx, ng + dy, oct, 32 + lm + dx);
      acc[0][0] = MFMA32(a0, b0, acc[0][0]);
      acc[0][1] = MFMA32(a0, b1, acc[0][1]);
      acc[1][0] = MFMA32(a1, b0, acc[1][0]);
      acc[1][1] = MFMA32(a1, b1, acc[1][1]);
    }
    __builtin_amdgcn_s_setprio(0);
    if (tap < 8) {
      SCHED0; BAR;
      stw_q(ldsw, r, tid);
      if (tap < 7) ldw_g_q(r, wq, tap + 2, tid);
      SCHED0; LGKM0; BAR; SCHED0;
    }
  }

  float g = gamma[0];
  const float* sb = s_in + (b * 16 + t) * 64;
  int w = w0 + ng;
  #pragma unroll
  for (int mt = 0; mt < 2; ++mt) {
    #pragma unroll
    for (int q = 0; q < 16; ++q) {
      int cl = (q & 3) + 8 * (q >> 2) + 4 * lh;
      int c  = mt * 32 + cl;
      float qb = bq[c], sc = sb[c];
      #pragma unroll
      for (int nt = 0; nt < 2; ++nt) {
        int h = nt * 32 + lm;
        uint32_t xb = (uint32_t)(((ng + 1) * 8 + (c >> 3)) * 66 + (h + 1)) * 16u
                    + (uint32_t)(c & 7) * 2u;
        float xv = bf2f(*(const uint16_t*)(ldsx + xb));
        size_t idx = ((size_t)(b * 64 + c) * 16 + t) * 4096 + (size_t)w * 64 + h;
        out[idx] = g * (acc[mt][nt][q] + qb) * sc + xv;
      }
    }
  }
}

extern "C" void kernel_launch(void* const* d_in, const int* in_sizes, int n_in,
                              void* d_out, int out_size, void* d_ws, size_t ws_size,
                              hipStream_t stream) {
  const float* x   = (const float*)d_in[0];
  const float* wq  = (const float*)d_in[1];
  const float* wk  = (const float*)d_in[2];
  const float* wv  = (const float*)d_in[3];
  const float* bq  = (const float*)d_in[4];
  const float* bk  = (const float*)d_in[5];
  const float* bv  = (const float*)d_in[6];
  const float* gam = (const float*)d_in[7];

  uint16_t* wbf = (uint16_t*)d_ws;                    // 221184 B
  float* sbuf   = (float*)((uint8_t*)d_ws + 221184);  // 32 KB
  uint8_t* xT   = (uint8_t*)d_ws + 1048576;           // 128 * 557568 = 71.4 MB
  if (ws_size < (size_t)1048576 + 128 * (size_t)SLICE_B) return;  // fail loudly

  hipMemsetAsync(sbuf, 0, 8 * 16 * 64 * sizeof(float), stream);
  prep_weights<<<(110592 + 255) / 256, 256, 0, stream>>>(wq, wk, wv, wbf);
  transpose_x<<<128 * 17, 256, 0, stream>>>(x, xT);
  kv_s_kernel<<<1024, 1024, LDSX10 + 32768, stream>>>(xT, wbf + 36864, bk, bv, sbuf);
  q_out_kernel<<<2048, 256, LDSX6 + 8192, stream>>>(xT, wbf, bq, sbuf, gam, (float*)d_out);
}

// Round 19
// 180.175 us; speedup vs baseline: 1.6598x; 1.0088x over previous
//
#include <hip/hip_runtime.h>
#include <hip/hip_bf16.h>
#include <stdint.h>

typedef __attribute__((ext_vector_type(8))) short bf16x8;
typedef __attribute__((ext_vector_type(4))) float f32x4v;
typedef __attribute__((ext_vector_type(16))) float f32x16;

#define CH_STRIDE 65536   // x: T*W*H floats per channel
#define ROW_B 8448        // xT bytes per w' row = 8*66*16
#define SLICE_B 557568    // xT bytes per slice = 66 rows * ROW_B

__device__ __forceinline__ uint16_t f2bf(float f) {
  uint32_t u = __builtin_bit_cast(uint32_t, f);
  u = (u + 0x7FFFu + ((u >> 16) & 1u)) >> 16;
  return (uint16_t)u;
}
__device__ __forceinline__ float bf2f(uint32_t b) {
  return __builtin_bit_cast(float, b << 16);
}
__device__ __forceinline__ uint16_t cvt_bf(float f) {
  return __builtin_bit_cast(uint16_t, __float2bfloat16(f));
}

#define MFMA32(a, b, c) __builtin_amdgcn_mfma_f32_32x32x16_bf16(a, b, c, 0, 0, 0)
#define WAIT0 asm volatile("s_waitcnt vmcnt(0) lgkmcnt(0)" ::: "memory")
#define BAR __builtin_amdgcn_s_barrier()
#define SCHED0 __builtin_amdgcn_sched_barrier(0)

#define LDSX6  (6 * 8 * 66 * 16)   // 50688 (q kernel x tile)
#define LDSX10 (10 * 8 * 66 * 16)  // 84480 (kv kernel x tile)

// Direct global->LDS DMA, 16B per lane. LDS dest = wave-uniform base + lane*16
// (our tid-linear staging satisfies this exactly).
__device__ __forceinline__ void gld16(const void* g, void* l) {
  __builtin_amdgcn_global_load_lds(
      (const __attribute__((address_space(1))) uint32_t*)g,
      (__attribute__((address_space(3))) uint32_t*)l, 16, 0, 0);
}

// x tile in LDS: [row][oct][col66] 16B frags, LINEAR.
__device__ __forceinline__ bf16x8 ldx(const uint8_t* ldsx, int row, int oct, int ci) {
  return *(const bf16x8*)(ldsx + (uint32_t)((row * 8 + oct) * 66 + ci) * 16u);
}
__device__ __forceinline__ bf16x8 ldw_kv(const uint8_t* ldsw, int oct, int rowloc) {
  return *(const bf16x8*)(ldsw + (uint32_t)(oct * 128 + rowloc) * 16u);
}
__device__ __forceinline__ bf16x8 ldw_q(const uint8_t* ldsw, int oct, int row) {
  return *(const bf16x8*)(ldsw + (uint32_t)(oct * 64 + row) * 16u);
}

// ---------------------------------------------------------------------------
// prep: fp32 [o][i][tap] -> bf16 tap-contiguous tables (q then kv).
// ---------------------------------------------------------------------------
__global__ void prep_weights(const float* __restrict__ wq, const float* __restrict__ wk,
                             const float* __restrict__ wv, uint16_t* __restrict__ wout) {
  int i = blockIdx.x * 256 + threadIdx.x;
  if (i >= 110592) return;
  if (i < 36864) {
    int tap = i >> 12, oct = (i >> 9) & 7, row = (i >> 3) & 63, j = i & 7;
    wout[i] = f2bf(wq[(row * 64 + oct * 8 + j) * 9 + tap]);
  } else {
    int m = i - 36864;
    int tap = m >> 13, oct = (m >> 10) & 7, rl = (m >> 3) & 127, j = m & 7;
    const float* src = (rl < 64) ? wk : wv;
    wout[i] = f2bf(src[((rl & 63) * 64 + oct * 8 + j) * 9 + tap]);
  }
}

// ---------------------------------------------------------------------------
// transpose_x: x fp32 -> xT bf16 [slice][w' 0..65][oct][col66] 16B frags.
// Direct register->global writes (unit's 4 frags = 64B contiguous; 16 lanes
// of same (row,oct) = 1KB contiguous). No LDS round-trip.
// ---------------------------------------------------------------------------
__global__ __launch_bounds__(256, 4) void transpose_x(const float* __restrict__ x,
                                                      uint8_t* __restrict__ xT) {
  const int tid = threadIdx.x;
  const int bid = blockIdx.x;
  const int gg = bid % 17, slice = bid / 17;
  const int b = slice >> 4, t = slice & 15;
  const int r0 = gg * 4;
  const int nrow = (gg == 16) ? 2 : 4;
  const float* xs = x + ((size_t)b * 1024 + t) * 4096;
  uint8_t* dst = xT + (size_t)slice * SLICE_B + (size_t)r0 * ROW_B;

  if (tid < nrow * 16) {  // col halos (ci = 0, 65)
    int row = tid >> 4, rem = tid & 15;
    int oct = rem >> 1, side = rem & 1;
    bf16x8 z = {};
    *(bf16x8*)(dst + (uint32_t)((row * 8 + oct) * 66 + side * 65) * 16u) = z;
  }
  #pragma unroll
  for (int k = 0; k < 2; ++k) {
    int u = tid + k * 256;
    if (u < nrow * 128) {
      int row = u >> 7, oct = (u >> 4) & 7, g = u & 15;
      int w = r0 + row - 1;  // w' = r0+row
      uint8_t* base = dst + (uint32_t)((row * 8 + oct) * 66 + 4 * g + 1) * 16u;
      if ((unsigned)w < 64u) {
        const float* p = xs + (size_t)(oct * 8) * CH_STRIDE + w * 64 + 4 * g;
        f32x4v v[8];
        #pragma unroll
        for (int j = 0; j < 8; ++j) v[j] = *(const f32x4v*)(p + (size_t)j * CH_STRIDE);
        #pragma unroll
        for (int c = 0; c < 4; ++c) {
          bf16x8 frag;
          #pragma unroll
          for (int q = 0; q < 4; ++q) {
            frag[2 * q]     = (short)cvt_bf(v[2 * q][c]);
            frag[2 * q + 1] = (short)cvt_bf(v[2 * q + 1][c]);
          }
          *(bf16x8*)(base + (uint32_t)c * 16u) = frag;
        }
      } else {
        bf16x8 z = {};
        #pragma unroll
        for (int c = 0; c < 4; ++c) *(bf16x8*)(base + (uint32_t)c * 16u) = z;
      }
    }
  }
}

// ---------------------------------------------------------------------------
// KV kernel: 1024 thr / 16 waves; 8-row tile. x stage AND per-tap weight
// prefetch via global_load_lds DMA (no VGPR roundtrip); dbuf weights,
// one barrier per tap; vmcnt(0) at tap end (DMA issued a full tap earlier).
// ---------------------------------------------------------------------------
__global__ __launch_bounds__(1024, 4) void kv_s_kernel(
    const uint8_t* __restrict__ xT, const uint16_t* __restrict__ wkv,
    const float* __restrict__ bk, const float* __restrict__ bv,
    float* __restrict__ s_out) {
  extern __shared__ uint8_t lds[];
  uint8_t* ldsx = lds;
  uint8_t* ldswA = lds + LDSX10;
  uint8_t* ldswB = lds + LDSX10 + 16384;
  const int tid = threadIdx.x;
  const int l = tid & 63;
  const int wid = tid >> 6;
  const int ng = wid & 7, mg = wid >> 3;
  int bid = (int)(blockIdx.x & 7) * 128 + (int)(blockIdx.x >> 3);  // XCD swizzle
  const int rg = bid & 7, slice = bid >> 3;
  const int b = slice >> 4, t = slice & 15;
  const int w0 = rg * 8;
  const int lm = l & 31, lh = l >> 5;

  // stage: 84480 contiguous bytes xT -> ldsx via DMA
  const uint8_t* gx = xT + (size_t)slice * SLICE_B + (size_t)w0 * ROW_B;
  #pragma unroll
  for (int k = 0; k < 6; ++k) {
    int idx = tid + k * 1024;
    if (idx < 5280) gld16(gx + (uint32_t)idx * 16u, ldsx + (uint32_t)idx * 16u);
  }
  gld16(wkv + (size_t)tid * 8, ldswA + (uint32_t)tid * 16u);  // tap 0 (16KB)
  SCHED0; WAIT0; BAR; SCHED0;

  f32x16 accK[2], accV[2];
  #pragma unroll
  for (int nt = 0; nt < 2; ++nt)
    #pragma unroll
    for (int q = 0; q < 16; ++q) { accK[nt][q] = 0.f; accV[nt][q] = 0.f; }

  #pragma unroll
  for (int tap = 0; tap < 9; ++tap) {
    const int dy = tap / 3, dx = tap % 3;
    const uint8_t* bufc = (tap & 1) ? ldswB : ldswA;
    uint8_t* bufn = (tap & 1) ? ldswA : ldswB;
    if (tap < 8)  // DMA tap+1 weights; rides under this tap's MFMA
      gld16(wkv + ((size_t)(tap + 1) * 1024 + tid) * 8, bufn + (uint32_t)tid * 16u);
    __builtin_amdgcn_s_setprio(1);
    #pragma unroll
    for (int s = 0; s < 4; ++s) {
      int oct = s * 2 + lh;
      bf16x8 aK = ldw_kv(bufc, oct, mg * 32 + lm);
      bf16x8 aV = ldw_kv(bufc, oct, 64 + mg * 32 + lm);
      bf16x8 b0 = ldx(ldsx, ng + dy, oct, lm + dx);
      bf16x8 b1 = ldx(ldsx, ng + dy, oct, 32 + lm + dx);
      accK[0] = MFMA32(aK, b0, accK[0]);
      accK[1] = MFMA32(aK, b1, accK[1]);
      accV[0] = MFMA32(aV, b0, accV[0]);
      accV[1] = MFMA32(aV, b1, accV[1]);
    }
    __builtin_amdgcn_s_setprio(0);
    SCHED0; WAIT0; BAR; SCHED0;
  }

  // epilogue: LDS partial-dump (stride 261), 64-thread reduce, 1 atomic/ch
  __syncthreads();
  float* red = (float*)lds;        // [c 64][261] = 66.8 KB
  #pragma unroll
  for (int q = 0; q < 16; ++q) {
    int cl = (q & 3) + 8 * (q >> 2) + 4 * lh;
    int c = mg * 32 + cl;
    float bkc = bk[c], bvc = bv[c];
    float p = (accK[0][q] + bkc) * (accV[0][q] + bvc)
            + (accK[1][q] + bkc) * (accV[1][q] + bvc);
    red[c * 261 + ng * 32 + lm] = p;
  }
  __syncthreads();
  if (tid < 64) {
    const float* rp = red + tid * 261;
    f32x4v a4 = {0.f, 0.f, 0.f, 0.f};
    #pragma unroll
    for (int j = 0; j < 64; ++j) a4 += *(const f32x4v*)(rp + j * 4);
    atomicAdd(s_out + (b * 16 + t) * 64 + tid, a4[0] + a4[1] + a4[2] + a4[3]);
  }
}

// ---------------------------------------------------------------------------
// Q kernel: 256 thr; stage + weights via DMA; dbuf weights, 1 barrier/tap.
// ---------------------------------------------------------------------------
__global__ __launch_bounds__(256, 2) void q_out_kernel(
    const uint8_t* __restrict__ xT, const uint16_t* __restrict__ wq,
    const float* __restrict__ bq, const float* __restrict__ s_in,
    const float* __restrict__ gamma, float* __restrict__ out) {
  extern __shared__ uint8_t lds[];
  uint8_t* ldsx = lds;
  uint8_t* ldswA = lds + LDSX6;
  uint8_t* ldswB = lds + LDSX6 + 8192;
  const int tid = threadIdx.x;
  const int l = tid & 63, ng = tid >> 6;
  int bid = (int)(blockIdx.x & 7) * 256 + (int)(blockIdx.x >> 3);  // XCD swizzle
  const int rg = bid & 15, slice = bid >> 4;
  const int b = slice >> 4, t = slice & 15;
  const int w0 = rg * 4;
  const int lm = l & 31, lh = l >> 5;

  const uint8_t* gx = xT + (size_t)slice * SLICE_B + (size_t)w0 * ROW_B;
  #pragma unroll
  for (int k = 0; k < 13; ++k) {
    int idx = tid + k * 256;
    if (idx < 3168) gld16(gx + (uint32_t)idx * 16u, ldsx + (uint32_t)idx * 16u);
  }
  #pragma unroll
  for (int k = 0; k < 2; ++k)  // tap 0 weights (8KB)
    gld16(wq + (size_t)(tid + k * 256) * 8, ldswA + (uint32_t)(tid + k * 256) * 16u);
  SCHED0; WAIT0; BAR; SCHED0;

  f32x16 acc[2][2];
  #pragma unroll
  for (int mt = 0; mt < 2; ++mt)
    #pragma unroll
    for (int nt = 0; nt < 2; ++nt)
      #pragma unroll
      for (int q = 0; q < 16; ++q) acc[mt][nt][q] = 0.f;

  #pragma unroll
  for (int tap = 0; tap < 9; ++tap) {
    const int dy = tap / 3, dx = tap % 3;
    const uint8_t* bufc = (tap & 1) ? ldswB : ldswA;
    uint8_t* bufn = (tap & 1) ? ldswA : ldswB;
    if (tap < 8) {
      #pragma unroll
      for (int k = 0; k < 2; ++k)
        gld16(wq + ((size_t)(tap + 1) * 512 + tid + k * 256) * 8,
              bufn + (uint32_t)(tid + k * 256) * 16u);
    }
    __builtin_amdgcn_s_setprio(1);
    #pragma unroll
    for (int s = 0; s < 4; ++s) {
      int oct = s * 2 + lh;
      bf16x8 a0 = ldw_q(bufc, oct, lm);
      bf16x8 a1 = ldw_q(bufc, oct, 32 + lm);
      bf16x8 b0 = ldx(ldsx, ng + dy, oct, lm + dx);
      bf16x8 b1 = ldx(ldsx, ng + dy, oct, 32 + lm + dx);
      acc[0][0] = MFMA32(a0, b0, acc[0][0]);
      acc[0][1] = MFMA32(a0, b1, acc[0][1]);
      acc[1][0] = MFMA32(a1, b0, acc[1][0]);
      acc[1][1] = MFMA32(a1, b1, acc[1][1]);
    }
    __builtin_amdgcn_s_setprio(0);
    SCHED0; WAIT0; BAR; SCHED0;
  }

  float g = gamma[0];
  const float* sb = s_in + (b * 16 + t) * 64;
  int w = w0 + ng;
  #pragma unroll
  for (int mt = 0; mt < 2; ++mt) {
    #pragma unroll
    for (int q = 0; q < 16; ++q) {
      int cl = (q & 3) + 8 * (q >> 2) + 4 * lh;
      int c  = mt * 32 + cl;
      float qb = bq[c], sc = sb[c];
      #pragma unroll
      for (int nt = 0; nt < 2; ++nt) {
        int h = nt * 32 + lm;
        uint32_t xb = (uint32_t)(((ng + 1) * 8 + (c >> 3)) * 66 + (h + 1)) * 16u
                    + (uint32_t)(c & 7) * 2u;
        float xv = bf2f(*(const uint16_t*)(ldsx + xb));
        size_t idx = ((size_t)(b * 64 + c) * 16 + t) * 4096 + (size_t)w * 64 + h;
        out[idx] = g * (acc[mt][nt][q] + qb) * sc + xv;
      }
    }
  }
}

extern "C" void kernel_launch(void* const* d_in, const int* in_sizes, int n_in,
                              void* d_out, int out_size, void* d_ws, size_t ws_size,
                              hipStream_t stream) {
  const float* x   = (const float*)d_in[0];
  const float* wq  = (const float*)d_in[1];
  const float* wk  = (const float*)d_in[2];
  const float* wv  = (const float*)d_in[3];
  const float* bq  = (const float*)d_in[4];
  const float* bk  = (const float*)d_in[5];
  const float* bv  = (const float*)d_in[6];
  const float* gam = (const float*)d_in[7];

  uint16_t* wbf = (uint16_t*)d_ws;                    // 221184 B
  float* sbuf   = (float*)((uint8_t*)d_ws + 221184);  // 32 KB
  uint8_t* xT   = (uint8_t*)d_ws + 1048576;           // 128 * 557568 = 71.4 MB
  if (ws_size < (size_t)1048576 + 128 * (size_t)SLICE_B) return;  // fail loudly

  hipMemsetAsync(sbuf, 0, 8 * 16 * 64 * sizeof(float), stream);
  prep_weights<<<(110592 + 255) / 256, 256, 0, stream>>>(wq, wk, wv, wbf);
  transpose_x<<<128 * 17, 256, 0, stream>>>(x, xT);
  kv_s_kernel<<<1024, 1024, LDSX10 + 32768, stream>>>(xT, wbf + 36864, bk, bv, sbuf);
  q_out_kernel<<<2048, 256, LDSX6 + 16384, stream>>>(xT, wbf, bq, sbuf, gam, (float*)d_out);
}

// Round 20
// 153.186 us; speedup vs baseline: 1.9522x; 1.1762x over previous
//
#include <hip/hip_runtime.h>
#include <hip/hip_bf16.h>
#include <stdint.h>

typedef __attribute__((ext_vector_type(8))) short bf16x8;
typedef __attribute__((ext_vector_type(4))) float f32x4v;
typedef __attribute__((ext_vector_type(16))) float f32x16;

#define CH_STRIDE 65536  // T*W*H

__device__ __forceinline__ uint16_t f2bf(float f) {
  uint32_t u = __builtin_bit_cast(uint32_t, f);
  u = (u + 0x7FFFu + ((u >> 16) & 1u)) >> 16;
  return (uint16_t)u;
}
__device__ __forceinline__ float bf2f(uint32_t b) {
  return __builtin_bit_cast(float, b << 16);
}
__device__ __forceinline__ uint16_t cvt_bf(float f) {
  return __builtin_bit_cast(uint16_t, __float2bfloat16(f));
}

#define MFMA32(a, b, c) __builtin_amdgcn_mfma_f32_32x32x16_bf16(a, b, c, 0, 0, 0)
#define WAIT0 asm volatile("s_waitcnt vmcnt(0) lgkmcnt(0)" ::: "memory")
#define BAR __builtin_amdgcn_s_barrier()
#define SCHED0 __builtin_amdgcn_sched_barrier(0)

#define LDSX6  (6 * 8 * 66 * 16)   // 50688 (q x tile)
#define LDSX10 (10 * 8 * 66 * 16)  // 84480 (kv x tile)

// Direct global->LDS DMA, 16B/lane (weights only — linear pattern).
__device__ __forceinline__ void gld16(const void* g, void* l) {
  __builtin_amdgcn_global_load_lds(
      (const __attribute__((address_space(1))) uint32_t*)g,
      (__attribute__((address_space(3))) uint32_t*)l, 16, 0, 0);
}

// x tile LDS: [row][oct][col66] 16B frags, LINEAR (frag-granular writes and
// contiguous-run reads are both conflict-free; verified 0 conflicts R18/R19).
__device__ __forceinline__ bf16x8 ldx(const uint8_t* ldsx, int row, int oct, int ci) {
  return *(const bf16x8*)(ldsx + (uint32_t)((row * 8 + oct) * 66 + ci) * 16u);
}
__device__ __forceinline__ bf16x8 ldw_kv(const uint8_t* ldsw, int oct, int rowloc) {
  return *(const bf16x8*)(ldsw + (uint32_t)(oct * 128 + rowloc) * 16u);
}
__device__ __forceinline__ bf16x8 ldw_q(const uint8_t* ldsw, int oct, int row) {
  return *(const bf16x8*)(ldsw + (uint32_t)(oct * 64 + row) * 16u);
}

// scatter staging unit: (row, oct, colgroup g) -> 8 dwordx4 fp32 loads,
// 4 linear b128 writes (bf16 convert in regs).
__device__ __forceinline__ void stage_unit(uint8_t* ldsx, const float* xs, int w0, int u) {
  int row = u >> 7, oct = (u >> 4) & 7, g = u & 15;
  int w = w0 - 1 + row;
  uint32_t base = (uint32_t)((row * 8 + oct) * 66 + 4 * g + 1) * 16u;
  if ((unsigned)w < 64u) {
    const float* p = xs + (size_t)(oct * 8) * CH_STRIDE + w * 64 + 4 * g;
    f32x4v v[8];
    #pragma unroll
    for (int j = 0; j < 8; ++j) v[j] = *(const f32x4v*)(p + (size_t)j * CH_STRIDE);
    #pragma unroll
    for (int c = 0; c < 4; ++c) {
      bf16x8 frag;
      #pragma unroll
      for (int q = 0; q < 4; ++q) {
        frag[2 * q]     = (short)cvt_bf(v[2 * q][c]);
        frag[2 * q + 1] = (short)cvt_bf(v[2 * q + 1][c]);
      }
      *(bf16x8*)(ldsx + base + (uint32_t)c * 16u) = frag;
    }
  } else {
    bf16x8 z = {};
    #pragma unroll
    for (int c = 0; c < 4; ++c) *(bf16x8*)(ldsx + base + (uint32_t)c * 16u) = z;
  }
}
__device__ __forceinline__ void stage_halo(uint8_t* ldsx, int tid, int nrow) {
  if (tid < nrow * 16) {
    int row = tid >> 4, rem = tid & 15;
    int oct = rem >> 1, side = rem & 1;
    bf16x8 z = {};
    *(bf16x8*)(ldsx + (uint32_t)((row * 8 + oct) * 66 + side * 65) * 16u) = z;
  }
}

// ---------------------------------------------------------------------------
// prep: fp32 [o][i][tap] -> bf16 tap-contiguous tables (q then kv).
// ---------------------------------------------------------------------------
__global__ void prep_weights(const float* __restrict__ wq, const float* __restrict__ wk,
                             const float* __restrict__ wv, uint16_t* __restrict__ wout) {
  int i = blockIdx.x * 256 + threadIdx.x;
  if (i >= 110592) return;
  if (i < 36864) {
    int tap = i >> 12, oct = (i >> 9) & 7, row = (i >> 3) & 63, j = i & 7;
    wout[i] = f2bf(wq[(row * 64 + oct * 8 + j) * 9 + tap]);
  } else {
    int m = i - 36864;
    int tap = m >> 13, oct = (m >> 10) & 7, rl = (m >> 3) & 127, j = m & 7;
    const float* src = (rl < 64) ? wk : wv;
    wout[i] = f2bf(src[((rl & 63) * 64 + oct * 8 + j) * 9 + tap]);
  }
}

// ---------------------------------------------------------------------------
// KV kernel: 512 thr / 8 waves; wave = 1 output row, owns ALL 4 weight
// tiles (K-lo,K-hi,V-lo,V-hi): 6 LDS reads -> 8 MFMA (0.75 reads/MFMA).
// Scatter x stage; dbuf weights via DMA; 1 barrier/tap.
// ---------------------------------------------------------------------------
__global__ __launch_bounds__(512, 2) void kv_s_kernel(
    const float* __restrict__ x, const uint16_t* __restrict__ wkv,
    const float* __restrict__ bk, const float* __restrict__ bv,
    float* __restrict__ s_out) {
  extern __shared__ uint8_t lds[];
  uint8_t* ldsx = lds;
  uint8_t* ldswA = lds + LDSX10;
  uint8_t* ldswB = lds + LDSX10 + 16384;
  const int tid = threadIdx.x;
  const int l = tid & 63;
  const int ng = tid >> 6;  // wave = output row 0..7
  int bid = (int)(blockIdx.x & 7) * 128 + (int)(blockIdx.x >> 3);  // XCD swizzle
  const int rg = bid & 7, slice = bid >> 3;
  const int b = slice >> 4, t = slice & 15;
  const int w0 = rg * 8;
  const float* xs = x + ((size_t)b * 1024 + t) * 4096;
  const int lm = l & 31, lh = l >> 5;

  // weights tap0 via DMA (16KB), then scatter-stage x (10 rows)
  gld16(wkv + (size_t)tid * 8, ldswA + (uint32_t)tid * 16u);
  gld16(wkv + (size_t)(tid + 512) * 8, ldswA + (uint32_t)(tid + 512) * 16u);
  stage_halo(ldsx, tid, 10);
  #pragma unroll
  for (int k = 0; k < 3; ++k) {
    int u = tid + k * 512;
    if (u < 1280) stage_unit(ldsx, xs, w0, u);
  }
  SCHED0; WAIT0; BAR; SCHED0;

  f32x16 accK[2][2], accV[2][2];  // [mt channel-half][nt col-half]
  #pragma unroll
  for (int mt = 0; mt < 2; ++mt)
    #pragma unroll
    for (int nt = 0; nt < 2; ++nt)
      #pragma unroll
      for (int q = 0; q < 16; ++q) { accK[mt][nt][q] = 0.f; accV[mt][nt][q] = 0.f; }

  #pragma unroll
  for (int tap = 0; tap < 9; ++tap) {
    const int dy = tap / 3, dx = tap % 3;
    const uint8_t* bufc = (tap & 1) ? ldswB : ldswA;
    uint8_t* bufn = (tap & 1) ? ldswA : ldswB;
    if (tap < 8) {  // DMA tap+1 weights; rides under this tap's MFMA
      gld16(wkv + ((size_t)(tap + 1) * 1024 + tid) * 8, bufn + (uint32_t)tid * 16u);
      gld16(wkv + ((size_t)(tap + 1) * 1024 + tid + 512) * 8,
            bufn + (uint32_t)(tid + 512) * 16u);
    }
    __builtin_amdgcn_s_setprio(1);
    #pragma unroll
    for (int s = 0; s < 4; ++s) {
      int oct = s * 2 + lh;
      bf16x8 aK0 = ldw_kv(bufc, oct, lm);
      bf16x8 aK1 = ldw_kv(bufc, oct, 32 + lm);
      bf16x8 aV0 = ldw_kv(bufc, oct, 64 + lm);
      bf16x8 aV1 = ldw_kv(bufc, oct, 96 + lm);
      bf16x8 b0  = ldx(ldsx, ng + dy, oct, lm + dx);
      bf16x8 b1  = ldx(ldsx, ng + dy, oct, 32 + lm + dx);
      accK[0][0] = MFMA32(aK0, b0, accK[0][0]);
      accK[0][1] = MFMA32(aK0, b1, accK[0][1]);
      accK[1][0] = MFMA32(aK1, b0, accK[1][0]);
      accK[1][1] = MFMA32(aK1, b1, accK[1][1]);
      accV[0][0] = MFMA32(aV0, b0, accV[0][0]);
      accV[0][1] = MFMA32(aV0, b1, accV[0][1]);
      accV[1][0] = MFMA32(aV1, b0, accV[1][0]);
      accV[1][1] = MFMA32(aV1, b1, accV[1][1]);
    }
    __builtin_amdgcn_s_setprio(0);
    SCHED0; WAIT0; BAR; SCHED0;
  }

  // epilogue: LDS partial-dump (stride 261), 64-thread reduce, 1 atomic/ch
  __syncthreads();
  float* red = (float*)lds;        // [c 64][261]
  #pragma unroll
  for (int q = 0; q < 16; ++q) {
    int cl = (q & 3) + 8 * (q >> 2) + 4 * lh;
    #pragma unroll
    for (int mt = 0; mt < 2; ++mt) {
      int c = mt * 32 + cl;
      float bkc = bk[c], bvc = bv[c];
      float p = (accK[mt][0][q] + bkc) * (accV[mt][0][q] + bvc)
              + (accK[mt][1][q] + bkc) * (accV[mt][1][q] + bvc);
      red[c * 261 + ng * 32 + lm] = p;
    }
  }
  __syncthreads();
  if (tid < 64) {
    const float* rp = red + tid * 261;
    f32x4v a4 = {0.f, 0.f, 0.f, 0.f};
    #pragma unroll
    for (int j = 0; j < 64; ++j) a4 += *(const f32x4v*)(rp + j * 4);
    atomicAdd(s_out + (b * 16 + t) * 64 + tid, a4[0] + a4[1] + a4[2] + a4[3]);
  }
}

// ---------------------------------------------------------------------------
// Q kernel: 256 thr / 4 waves; scatter stage; dbuf DMA weights; fused
// epilogue with residual from LDS tile. (R16/R19 hybrid, known-good.)
// ---------------------------------------------------------------------------
__global__ __launch_bounds__(256, 2) void q_out_kernel(
    const float* __restrict__ x, const uint16_t* __restrict__ wq,
    const float* __restrict__ bq, const float* __restrict__ s_in,
    const float* __restrict__ gamma, float* __restrict__ out) {
  extern __shared__ uint8_t lds[];
  uint8_t* ldsx = lds;
  uint8_t* ldswA = lds + LDSX6;
  uint8_t* ldswB = lds + LDSX6 + 8192;
  const int tid = threadIdx.x;
  const int l = tid & 63, ng = tid >> 6;
  int bid = (int)(blockIdx.x & 7) * 256 + (int)(blockIdx.x >> 3);  // XCD swizzle
  const int rg = bid & 15, slice = bid >> 4;
  const int b = slice >> 4, t = slice & 15;
  const int w0 = rg * 4;
  const float* xs = x + ((size_t)b * 1024 + t) * 4096;
  const int lm = l & 31, lh = l >> 5;

  #pragma unroll
  for (int k = 0; k < 2; ++k)  // tap0 weights (8KB) via DMA
    gld16(wq + (size_t)(tid + k * 256) * 8, ldswA + (uint32_t)(tid + k * 256) * 16u);
  stage_halo(ldsx, tid, 6);
  #pragma unroll
  for (int k = 0; k < 3; ++k) stage_unit(ldsx, xs, w0, tid + k * 256);
  SCHED0; WAIT0; BAR; SCHED0;

  f32x16 acc[2][2];
  #pragma unroll
  for (int mt = 0; mt < 2; ++mt)
    #pragma unroll
    for (int nt = 0; nt < 2; ++nt)
      #pragma unroll
      for (int q = 0; q < 16; ++q) acc[mt][nt][q] = 0.f;

  #pragma unroll
  for (int tap = 0; tap < 9; ++tap) {
    const int dy = tap / 3, dx = tap % 3;
    const uint8_t* bufc = (tap & 1) ? ldswB : ldswA;
    uint8_t* bufn = (tap & 1) ? ldswA : ldswB;
    if (tap < 8) {
      #pragma unroll
      for (int k = 0; k < 2; ++k)
        gld16(wq + ((size_t)(tap + 1) * 512 + tid + k * 256) * 8,
              bufn + (uint32_t)(tid + k * 256) * 16u);
    }
    __builtin_amdgcn_s_setprio(1);
    #pragma unroll
    for (int s = 0; s < 4; ++s) {
      int oct = s * 2 + lh;
      bf16x8 a0 = ldw_q(bufc, oct, lm);
      bf16x8 a1 = ldw_q(bufc, oct, 32 + lm);
      bf16x8 b0 = ldx(ldsx, ng + dy, oct, lm + dx);
      bf16x8 b1 = ldx(ldsx, ng + dy, oct, 32 + lm + dx);
      acc[0][0] = MFMA32(a0, b0, acc[0][0]);
      acc[0][1] = MFMA32(a0, b1, acc[0][1]);
      acc[1][0] = MFMA32(a1, b0, acc[1][0]);
      acc[1][1] = MFMA32(a1, b1, acc[1][1]);
    }
    __builtin_amdgcn_s_setprio(0);
    SCHED0; WAIT0; BAR; SCHED0;
  }

  float g = gamma[0];
  const float* sb = s_in + (b * 16 + t) * 64;
  int w = w0 + ng;
  #pragma unroll
  for (int mt = 0; mt < 2; ++mt) {
    #pragma unroll
    for (int q = 0; q < 16; ++q) {
      int cl = (q & 3) + 8 * (q >> 2) + 4 * lh;
      int c  = mt * 32 + cl;
      float qb = bq[c], sc = sb[c];
      #pragma unroll
      for (int nt = 0; nt < 2; ++nt) {
        int h = nt * 32 + lm;
        uint32_t xb = (uint32_t)(((ng + 1) * 8 + (c >> 3)) * 66 + (h + 1)) * 16u
                    + (uint32_t)(c & 7) * 2u;
        float xv = bf2f(*(const uint16_t*)(ldsx + xb));
        size_t idx = ((size_t)(b * 64 + c) * 16 + t) * 4096 + (size_t)w * 64 + h;
        out[idx] = g * (acc[mt][nt][q] + qb) * sc + xv;
      }
    }
  }
}

extern "C" void kernel_launch(void* const* d_in, const int* in_sizes, int n_in,
                              void* d_out, int out_size, void* d_ws, size_t ws_size,
                              hipStream_t stream) {
  const float* x   = (const float*)d_in[0];
  const float* wq  = (const float*)d_in[1];
  const float* wk  = (const float*)d_in[2];
  const float* wv  = (const float*)d_in[3];
  const float* bq  = (const float*)d_in[4];
  const float* bk  = (const float*)d_in[5];
  const float* bv  = (const float*)d_in[6];
  const float* gam = (const float*)d_in[7];

  uint16_t* wbf = (uint16_t*)d_ws;                    // 221184 B
  float* sbuf   = (float*)((uint8_t*)d_ws + 221184);  // 32 KB

  hipMemsetAsync(sbuf, 0, 8 * 16 * 64 * sizeof(float), stream);
  prep_weights<<<(110592 + 255) / 256, 256, 0, stream>>>(wq, wk, wv, wbf);
  kv_s_kernel<<<1024, 512, LDSX10 + 32768, stream>>>(x, wbf + 36864, bk, bv, sbuf);
  q_out_kernel<<<2048, 256, LDSX6 + 16384, stream>>>(x, wbf, bq, sbuf, gam, (float*)d_out);
}

// Round 21
// 149.786 us; speedup vs baseline: 1.9965x; 1.0227x over previous
//
#include <hip/hip_runtime.h>
#include <hip/hip_bf16.h>
#include <stdint.h>

typedef __attribute__((ext_vector_type(8))) short bf16x8;
typedef __attribute__((ext_vector_type(4))) float f32x4v;
typedef __attribute__((ext_vector_type(16))) float f32x16;
typedef __attribute__((ext_vector_type(4))) unsigned int u32x4;

#define CH_STRIDE 65536  // T*W*H

__device__ __forceinline__ uint16_t f2bf(float f) {
  uint32_t u = __builtin_bit_cast(uint32_t, f);
  u = (u + 0x7FFFu + ((u >> 16) & 1u)) >> 16;
  return (uint16_t)u;
}
__device__ __forceinline__ float bf2f(uint32_t b) {
  return __builtin_bit_cast(float, b << 16);
}
__device__ __forceinline__ uint16_t cvt_bf(float f) {
  return __builtin_bit_cast(uint16_t, __float2bfloat16(f));
}
__device__ __forceinline__ bf16x8 andm(bf16x8 v, uint32_t m) {
  u32x4 u = __builtin_bit_cast(u32x4, v);
  u[0] &= m; u[1] &= m; u[2] &= m; u[3] &= m;
  return __builtin_bit_cast(bf16x8, u);
}

#define MFMA32(a, b, c) __builtin_amdgcn_mfma_f32_32x32x16_bf16(a, b, c, 0, 0, 0)
#define WAIT0 asm volatile("s_waitcnt vmcnt(0) lgkmcnt(0)" ::: "memory")
#define BAR __builtin_amdgcn_s_barrier()
#define SCHED0 __builtin_amdgcn_sched_barrier(0)

#define LDSX6  (6 * 8 * 66 * 16)   // 50688 (q x tile, WITH halo cols)
#define LDSK   (6 * 8 * 64 * 16)   // 49152 (kv x tile, interior only)

// Direct global->LDS DMA, 16B/lane (weights — linear pattern).
__device__ __forceinline__ void gld16(const void* g, void* l) {
  __builtin_amdgcn_global_load_lds(
      (const __attribute__((address_space(1))) uint32_t*)g,
      (__attribute__((address_space(3))) uint32_t*)l, 16, 0, 0);
}

// q x tile: [row][oct][col66] (halo cols 0,65 zero).
__device__ __forceinline__ bf16x8 ldx(const uint8_t* ldsx, int row, int oct, int ci) {
  return *(const bf16x8*)(ldsx + (uint32_t)((row * 8 + oct) * 66 + ci) * 16u);
}
// kv x tile: [row][oct][col64] interior only; caller clamps/masks.
__device__ __forceinline__ bf16x8 ldx64(const uint8_t* ldsx, int row, int oct, int ci) {
  return *(const bf16x8*)(ldsx + (uint32_t)((row * 8 + oct) * 64 + ci) * 16u);
}
__device__ __forceinline__ bf16x8 ldw_kv(const uint8_t* ldsw, int oct, int rowloc) {
  return *(const bf16x8*)(ldsw + (uint32_t)(oct * 128 + rowloc) * 16u);
}
__device__ __forceinline__ bf16x8 ldw_q(const uint8_t* ldsw, int oct, int row) {
  return *(const bf16x8*)(ldsw + (uint32_t)(oct * 64 + row) * 16u);
}

// scatter stage (q variant, 66-col with halo): (row, oct, g) unit
__device__ __forceinline__ void stage_unit66(uint8_t* ldsx, const float* xs, int w0, int u) {
  int row = u >> 7, oct = (u >> 4) & 7, g = u & 15;
  int w = w0 - 1 + row;
  uint32_t base = (uint32_t)((row * 8 + oct) * 66 + 4 * g + 1) * 16u;
  if ((unsigned)w < 64u) {
    const float* p = xs + (size_t)(oct * 8) * CH_STRIDE + w * 64 + 4 * g;
    f32x4v v[8];
    #pragma unroll
    for (int j = 0; j < 8; ++j) v[j] = *(const f32x4v*)(p + (size_t)j * CH_STRIDE);
    #pragma unroll
    for (int c = 0; c < 4; ++c) {
      bf16x8 frag;
      #pragma unroll
      for (int q = 0; q < 4; ++q) {
        frag[2 * q]     = (short)cvt_bf(v[2 * q][c]);
        frag[2 * q + 1] = (short)cvt_bf(v[2 * q + 1][c]);
      }
      *(bf16x8*)(ldsx + base + (uint32_t)c * 16u) = frag;
    }
  } else {
    bf16x8 z = {};
    #pragma unroll
    for (int c = 0; c < 4; ++c) *(bf16x8*)(ldsx + base + (uint32_t)c * 16u) = z;
  }
}
// scatter stage (kv variant, 64-col interior)
__device__ __forceinline__ void stage_unit64(uint8_t* ldsx, const float* xs, int w0, int u) {
  int row = u >> 7, oct = (u >> 4) & 7, g = u & 15;
  int w = w0 - 1 + row;
  uint32_t base = (uint32_t)((row * 8 + oct) * 64 + 4 * g) * 16u;
  if ((unsigned)w < 64u) {
    const float* p = xs + (size_t)(oct * 8) * CH_STRIDE + w * 64 + 4 * g;
    f32x4v v[8];
    #pragma unroll
    for (int j = 0; j < 8; ++j) v[j] = *(const f32x4v*)(p + (size_t)j * CH_STRIDE);
    #pragma unroll
    for (int c = 0; c < 4; ++c) {
      bf16x8 frag;
      #pragma unroll
      for (int q = 0; q < 4; ++q) {
        frag[2 * q]     = (short)cvt_bf(v[2 * q][c]);
        frag[2 * q + 1] = (short)cvt_bf(v[2 * q + 1][c]);
      }
      *(bf16x8*)(ldsx + base + (uint32_t)c * 16u) = frag;
    }
  } else {
    bf16x8 z = {};
    #pragma unroll
    for (int c = 0; c < 4; ++c) *(bf16x8*)(ldsx + base + (uint32_t)c * 16u) = z;
  }
}
__device__ __forceinline__ void stage_halo66(uint8_t* ldsx, int tid, int nrow) {
  if (tid < nrow * 16) {
    int row = tid >> 4, rem = tid & 15;
    int oct = rem >> 1, side = rem & 1;
    bf16x8 z = {};
    *(bf16x8*)(ldsx + (uint32_t)((row * 8 + oct) * 66 + side * 65) * 16u) = z;
  }
}

// ---------------------------------------------------------------------------
// prep: fp32 [o][i][tap] -> bf16 tap-contiguous tables (q then kv).
// ---------------------------------------------------------------------------
__global__ void prep_weights(const float* __restrict__ wq, const float* __restrict__ wk,
                             const float* __restrict__ wv, uint16_t* __restrict__ wout) {
  int i = blockIdx.x * 256 + threadIdx.x;
  if (i >= 110592) return;
  if (i < 36864) {
    int tap = i >> 12, oct = (i >> 9) & 7, row = (i >> 3) & 63, j = i & 7;
    wout[i] = f2bf(wq[(row * 64 + oct * 8 + j) * 9 + tap]);
  } else {
    int m = i - 36864;
    int tap = m >> 13, oct = (m >> 10) & 7, rl = (m >> 3) & 127, j = m & 7;
    const float* src = (rl < 64) ? wk : wv;
    wout[i] = f2bf(src[((rl & 63) * 64 + oct * 8 + j) * 9 + tap]);
  }
}

// ---------------------------------------------------------------------------
// KV kernel: 256 thr / 4 waves; wave = 1 output row (4-row tile); M=4 weight
// tiles per wave; LDS = 49152 + 2x16384 = 81920 B -> 2 blocks/CU so block B's
// stage overlaps block A's MFMA loop. h-halo via lane masks (no halo cols).
// ---------------------------------------------------------------------------
__global__ __launch_bounds__(256, 2) void kv_s_kernel(
    const float* __restrict__ x, const uint16_t* __restrict__ wkv,
    const float* __restrict__ bk, const float* __restrict__ bv,
    float* __restrict__ s_out) {
  extern __shared__ uint8_t lds[];
  uint8_t* ldsx = lds;
  uint8_t* ldswA = lds + LDSK;
  uint8_t* ldswB = lds + LDSK + 16384;
  const int tid = threadIdx.x;
  const int l = tid & 63;
  const int ng = tid >> 6;  // wave = output row 0..3
  int bid = (int)(blockIdx.x & 7) * 256 + (int)(blockIdx.x >> 3);  // XCD swizzle
  const int rg = bid & 15, slice = bid >> 4;
  const int b = slice >> 4, t = slice & 15;
  const int w0 = rg * 4;
  const float* xs = x + ((size_t)b * 1024 + t) * 4096;
  const int lm = l & 31, lh = l >> 5;
  const uint32_t mz0 = (lm == 0) ? 0u : ~0u;   // b0 halo mask at dx=0
  const uint32_t mz1 = (lm == 31) ? 0u : ~0u;  // b1 halo mask at dx=2

  // weights tap0 via DMA (16KB = 4 x 4KB), then scatter-stage x interior
  #pragma unroll
  for (int k = 0; k < 4; ++k)
    gld16(wkv + (size_t)(tid + k * 256) * 8, ldswA + (uint32_t)(tid + k * 256) * 16u);
  #pragma unroll
  for (int k = 0; k < 3; ++k) stage_unit64(ldsx, xs, w0, tid + k * 256);
  SCHED0; WAIT0; BAR; SCHED0;

  f32x16 accK[2][2], accV[2][2];  // [mt channel-half][nt col-half]
  #pragma unroll
  for (int mt = 0; mt < 2; ++mt)
    #pragma unroll
    for (int nt = 0; nt < 2; ++nt)
      #pragma unroll
      for (int q = 0; q < 16; ++q) { accK[mt][nt][q] = 0.f; accV[mt][nt][q] = 0.f; }

  #pragma unroll
  for (int tap = 0; tap < 9; ++tap) {
    const int dy = tap / 3, dx = tap % 3;
    const uint8_t* bufc = (tap & 1) ? ldswB : ldswA;
    uint8_t* bufn = (tap & 1) ? ldswA : ldswB;
    if (tap < 8) {  // DMA tap+1 weights; rides under this tap's MFMA
      #pragma unroll
      for (int k = 0; k < 4; ++k)
        gld16(wkv + ((size_t)(tap + 1) * 1024 + tid + k * 256) * 8,
              bufn + (uint32_t)(tid + k * 256) * 16u);
    }
    __builtin_amdgcn_s_setprio(1);
    #pragma unroll
    for (int s = 0; s < 4; ++s) {
      int oct = s * 2 + lh;
      bf16x8 aK0 = ldw_kv(bufc, oct, lm);
      bf16x8 aK1 = ldw_kv(bufc, oct, 32 + lm);
      bf16x8 aV0 = ldw_kv(bufc, oct, 64 + lm);
      bf16x8 aV1 = ldw_kv(bufc, oct, 96 + lm);
      bf16x8 b0  = ldx64(ldsx, ng + dy, oct, (lm + dx - 1) & 63);
      bf16x8 b1  = ldx64(ldsx, ng + dy, oct, (32 + lm + dx - 1) & 63);
      if (dx == 0) b0 = andm(b0, mz0);
      if (dx == 2) b1 = andm(b1, mz1);
      accK[0][0] = MFMA32(aK0, b0, accK[0][0]);
      accK[0][1] = MFMA32(aK0, b1, accK[0][1]);
      accK[1][0] = MFMA32(aK1, b0, accK[1][0]);
      accK[1][1] = MFMA32(aK1, b1, accK[1][1]);
      accV[0][0] = MFMA32(aV0, b0, accV[0][0]);
      accV[0][1] = MFMA32(aV0, b1, accV[0][1]);
      accV[1][0] = MFMA32(aV1, b0, accV[1][0]);
      accV[1][1] = MFMA32(aV1, b1, accV[1][1]);
    }
    __builtin_amdgcn_s_setprio(0);
    SCHED0; WAIT0; BAR; SCHED0;
  }

  // epilogue: LDS partial-dump (stride 133), 64-thread reduce, 1 atomic/ch
  __syncthreads();
  float* red = (float*)lds;        // [c 64][133] = 34 KB (fits ldsx region)
  #pragma unroll
  for (int q = 0; q < 16; ++q) {
    int cl = (q & 3) + 8 * (q >> 2) + 4 * lh;
    #pragma unroll
    for (int mt = 0; mt < 2; ++mt) {
      int c = mt * 32 + cl;
      float bkc = bk[c], bvc = bv[c];
      float p = (accK[mt][0][q] + bkc) * (accV[mt][0][q] + bvc)
              + (accK[mt][1][q] + bkc) * (accV[mt][1][q] + bvc);
      red[c * 133 + ng * 32 + lm] = p;
    }
  }
  __syncthreads();
  if (tid < 64) {
    const float* rp = red + tid * 133;
    f32x4v a4 = {0.f, 0.f, 0.f, 0.f};
    #pragma unroll
    for (int j = 0; j < 32; ++j) a4 += *(const f32x4v*)(rp + j * 4);
    atomicAdd(s_out + (b * 16 + t) * 64 + tid, a4[0] + a4[1] + a4[2] + a4[3]);
  }
}

// ---------------------------------------------------------------------------
// Q kernel: unchanged from R20 (passes at ~37us, already 2 blocks/CU).
// ---------------------------------------------------------------------------
__global__ __launch_bounds__(256, 2) void q_out_kernel(
    const float* __restrict__ x, const uint16_t* __restrict__ wq,
    const float* __restrict__ bq, const float* __restrict__ s_in,
    const float* __restrict__ gamma, float* __restrict__ out) {
  extern __shared__ uint8_t lds[];
  uint8_t* ldsx = lds;
  uint8_t* ldswA = lds + LDSX6;
  uint8_t* ldswB = lds + LDSX6 + 8192;
  const int tid = threadIdx.x;
  const int l = tid & 63, ng = tid >> 6;
  int bid = (int)(blockIdx.x & 7) * 256 + (int)(blockIdx.x >> 3);  // XCD swizzle
  const int rg = bid & 15, slice = bid >> 4;
  const int b = slice >> 4, t = slice & 15;
  const int w0 = rg * 4;
  const float* xs = x + ((size_t)b * 1024 + t) * 4096;
  const int lm = l & 31, lh = l >> 5;

  #pragma unroll
  for (int k = 0; k < 2; ++k)  // tap0 weights (8KB) via DMA
    gld16(wq + (size_t)(tid + k * 256) * 8, ldswA + (uint32_t)(tid + k * 256) * 16u);
  stage_halo66(ldsx, tid, 6);
  #pragma unroll
  for (int k = 0; k < 3; ++k) stage_unit66(ldsx, xs, w0, tid + k * 256);
  SCHED0; WAIT0; BAR; SCHED0;

  f32x16 acc[2][2];
  #pragma unroll
  for (int mt = 0; mt < 2; ++mt)
    #pragma unroll
    for (int nt = 0; nt < 2; ++nt)
      #pragma unroll
      for (int q = 0; q < 16; ++q) acc[mt][nt][q] = 0.f;

  #pragma unroll
  for (int tap = 0; tap < 9; ++tap) {
    const int dy = tap / 3, dx = tap % 3;
    const uint8_t* bufc = (tap & 1) ? ldswB : ldswA;
    uint8_t* bufn = (tap & 1) ? ldswA : ldswB;
    if (tap < 8) {
      #pragma unroll
      for (int k = 0; k < 2; ++k)
        gld16(wq + ((size_t)(tap + 1) * 512 + tid + k * 256) * 8,
              bufn + (uint32_t)(tid + k * 256) * 16u);
    }
    __builtin_amdgcn_s_setprio(1);
    #pragma unroll
    for (int s = 0; s < 4; ++s) {
      int oct = s * 2 + lh;
      bf16x8 a0 = ldw_q(bufc, oct, lm);
      bf16x8 a1 = ldw_q(bufc, oct, 32 + lm);
      bf16x8 b0 = ldx(ldsx, ng + dy, oct, lm + dx);
      bf16x8 b1 = ldx(ldsx, ng + dy, oct, 32 + lm + dx);
      acc[0][0] = MFMA32(a0, b0, acc[0][0]);
      acc[0][1] = MFMA32(a0, b1, acc[0][1]);
      acc[1][0] = MFMA32(a1, b0, acc[1][0]);
      acc[1][1] = MFMA32(a1, b1, acc[1][1]);
    }
    __builtin_amdgcn_s_setprio(0);
    SCHED0; WAIT0; BAR; SCHED0;
  }

  float g = gamma[0];
  const float* sb = s_in + (b * 16 + t) * 64;
  int w = w0 + ng;
  #pragma unroll
  for (int mt = 0; mt < 2; ++mt) {
    #pragma unroll
    for (int q = 0; q < 16; ++q) {
      int cl = (q & 3) + 8 * (q >> 2) + 4 * lh;
      int c  = mt * 32 + cl;
      float qb = bq[c], sc = sb[c];
      #pragma unroll
      for (int nt = 0; nt < 2; ++nt) {
        int h = nt * 32 + lm;
        uint32_t xb = (uint32_t)(((ng + 1) * 8 + (c >> 3)) * 66 + (h + 1)) * 16u
                    + (uint32_t)(c & 7) * 2u;
        float xv = bf2f(*(const uint16_t*)(ldsx + xb));
        size_t idx = ((size_t)(b * 64 + c) * 16 + t) * 4096 + (size_t)w * 64 + h;
        out[idx] = g * (acc[mt][nt][q] + qb) * sc + xv;
      }
    }
  }
}

extern "C" void kernel_launch(void* const* d_in, const int* in_sizes, int n_in,
                              void* d_out, int out_size, void* d_ws, size_t ws_size,
                              hipStream_t stream) {
  const float* x   = (const float*)d_in[0];
  const float* wq  = (const float*)d_in[1];
  const float* wk  = (const float*)d_in[2];
  const float* wv  = (const float*)d_in[3];
  const float* bq  = (const float*)d_in[4];
  const float* bk  = (const float*)d_in[5];
  const float* bv  = (const float*)d_in[6];
  const float* gam = (const float*)d_in[7];

  uint16_t* wbf = (uint16_t*)d_ws;                    // 221184 B
  float* sbuf   = (float*)((uint8_t*)d_ws + 221184);  // 32 KB

  hipMemsetAsync(sbuf, 0, 8 * 16 * 64 * sizeof(float), stream);
  prep_weights<<<(110592 + 255) / 256, 256, 0, stream>>>(wq, wk, wv, wbf);
  kv_s_kernel<<<2048, 256, LDSK + 32768, stream>>>(x, wbf + 36864, bk, bv, sbuf);
  q_out_kernel<<<2048, 256, LDSX6 + 16384, stream>>>(x, wbf, bq, sbuf, gam, (float*)d_out);
}